// Round 1
// baseline (771.485 us; speedup 1.0000x reference)
//
#include <hip/hip_runtime.h>
#include <hip/hip_bf16.h>
#include <math.h>

#define DD 128

// ---------------- K0: exclusive prefix scan of counts -> offs ----------------
__global__ void k0_scan(const int* __restrict__ counts, int* __restrict__ offs, int B)
{
    __shared__ int part[256];
    int t = threadIdx.x;
    int chunk = (B + 255) >> 8;
    int s = 0;
    for (int i = 0; i < chunk; ++i) {
        int idx = t * chunk + i;
        if (idx < B) s += counts[idx];
    }
    part[t] = s;
    __syncthreads();
    for (int off = 1; off < 256; off <<= 1) {
        int val = (t >= off) ? part[t - off] : 0;
        __syncthreads();
        part[t] += val;
        __syncthreads();
    }
    int run = (t > 0) ? part[t - 1] : 0;
    for (int i = 0; i < chunk; ++i) {
        int idx = t * chunk + i;
        if (idx < B) { offs[idx] = run; run += counts[idx]; }
    }
}

// ---------------- K1: per-graph mean + absmax ----------------
__global__ __launch_bounds__(128)
void k1_stats(const float* __restrict__ feats, const int* __restrict__ offs,
              const int* __restrict__ counts, float* __restrict__ mean,
              float* __restrict__ amax)
{
    int g = blockIdx.x;
    int d = threadIdx.x;
    int s = offs[g], c = counts[g];
    const float* p = feats + (size_t)s * DD + d;
    float sum = 0.f, mx = 0.f;   // |v| >= 0 so 0-init == segment_max(|.|)
    for (int i = 0; i < c; ++i) {
        float v = p[(size_t)i * DD];
        sum += v;
        mx = fmaxf(mx, fabsf(v));
    }
    mean[(size_t)g * DD + d] = sum / (float)c;
    amax[(size_t)g * DD + d] = mx;
}

// ---------------- K2: v[g] = row(g) @ W_v + b_v ----------------
// row(g) = (g odd) ? amax[g/2] : mean[g/2]   (replicates torch interleaved-table indexing)
__global__ __launch_bounds__(128)
void k2_vtab(const float* __restrict__ mean, const float* __restrict__ amax,
             const float* __restrict__ Wv, const float* __restrict__ bv,
             float* __restrict__ vtab, int B)
{
    __shared__ float rows[16][DD];
    int g0 = blockIdx.x * 16;
    int h = threadIdx.x;
    for (int i = 0; i < 16; ++i) {
        int g = g0 + i;
        float val = 0.f;
        if (g < B) {
            int gg = g >> 1;
            const float* src = (g & 1) ? &amax[(size_t)gg * DD] : &mean[(size_t)gg * DD];
            val = src[h];
        }
        rows[i][h] = val;
    }
    __syncthreads();
    float acc[16];
    float bvh = bv[h];
    #pragma unroll
    for (int i = 0; i < 16; ++i) acc[i] = bvh;
    for (int d = 0; d < DD; d += 2) {
        float w0 = Wv[(size_t)d * DD + h];
        float w1 = Wv[(size_t)(d + 1) * DD + h];
        #pragma unroll
        for (int i = 0; i < 16; ++i) {
            float2 r = *(const float2*)&rows[i][d];
            acc[i] = fmaf(r.x, w0, acc[i]);
            acc[i] = fmaf(r.y, w1, acc[i]);
        }
    }
    #pragma unroll
    for (int i = 0; i < 16; ++i) {
        int g = g0 + i;
        if (g < B) vtab[(size_t)g * DD + h] = acc[i];
    }
}

// ---------------- K3: fused feats@W_u + sigmoid + dot(w_e) + exp -> ee ----------------
// 128-node tile, A staged transposed in LDS [128k][132], 8x8 per-thread register tile.
__global__ __launch_bounds__(256, 2)
void k3_gemm(const float* __restrict__ feats, const float* __restrict__ Wu,
             const float* __restrict__ vtab, const float* __restrict__ we,
             const int* __restrict__ seg, float* __restrict__ ee, int N)
{
    extern __shared__ float A[];   // [128][132]
    const int t = threadIdx.x;
    const int n_base = blockIdx.x * 128;

    // stage feats tile transposed: A[d][n]
    for (int c = 0; c < 64; ++c) {
        int flat = c * 256 + t;
        int n = flat >> 7;
        int d = flat & 127;
        int gn = n_base + n;
        float val = (gn < N) ? feats[(size_t)gn * DD + d] : 0.f;
        A[d * 132 + n] = val;
    }
    __syncthreads();

    const int tx = t & 15;          // h direction
    const int ty = t >> 4;          // node direction
    const int h0 = tx * 8;
    const int nl0 = ty * 8;

    float acc[8][8];
    #pragma unroll
    for (int i = 0; i < 8; ++i)
        #pragma unroll
        for (int j = 0; j < 8; ++j) acc[i][j] = 0.f;

    #pragma unroll 4
    for (int k = 0; k < 128; ++k) {
        const float4 b0 = *(const float4*)&Wu[(size_t)k * DD + h0];
        const float4 b1 = *(const float4*)&Wu[(size_t)k * DD + h0 + 4];
        const float4 a0 = *(const float4*)&A[k * 132 + nl0];
        const float4 a1 = *(const float4*)&A[k * 132 + nl0 + 4];
        const float a[8] = {a0.x, a0.y, a0.z, a0.w, a1.x, a1.y, a1.z, a1.w};
        const float b[8] = {b0.x, b0.y, b0.z, b0.w, b1.x, b1.y, b1.z, b1.w};
        #pragma unroll
        for (int i = 0; i < 8; ++i)
            #pragma unroll
            for (int j = 0; j < 8; ++j)
                acc[i][j] = fmaf(a[i], b[j], acc[i][j]);
    }

    float wv[8];
    #pragma unroll
    for (int j = 0; j < 8; ++j) wv[j] = we[h0 + j];

    #pragma unroll
    for (int i = 0; i < 8; ++i) {
        int gn = n_base + nl0 + i;
        if (gn < N) {
            int g = seg[gn];
            const float* vg = &vtab[(size_t)g * DD + h0];
            float p = 0.f;
            #pragma unroll
            for (int j = 0; j < 8; ++j) {
                float x = acc[i][j] + vg[j];
                float sg = 1.f / (1.f + __expf(-x));
                p = fmaf(sg, wv[j], p);
            }
            // reduce over the 16 h-threads (same 16-lane group)
            p += __shfl_xor(p, 1);
            p += __shfl_xor(p, 2);
            p += __shfl_xor(p, 4);
            p += __shfl_xor(p, 8);
            if (tx == 0) {
                float eeo = (p != 0.f) ? __expf(p) : p;
                ee[gn] = eeo;
            }
        }
    }
}

// ---------------- K4: attention-weighted pooling (fused denominator) ----------------
__global__ __launch_bounds__(128)
void k4_pool(const float* __restrict__ feats, const float* __restrict__ ee,
             const int* __restrict__ offs, const int* __restrict__ counts,
             float* __restrict__ out)
{
    int g = blockIdx.x;
    int d = threadIdx.x;
    int s = offs[g], c = counts[g];
    const float* p = feats + (size_t)s * DD + d;
    const float* w = ee + s;
    float acc = 0.f, den = 0.f;
    for (int i = 0; i < c; ++i) {
        float wi = w[i];
        den += wi;
        acc = fmaf(p[(size_t)i * DD], wi, acc);
    }
    out[(size_t)g * DD + d] = acc / den;
}

extern "C" void kernel_launch(void* const* d_in, const int* in_sizes, int n_in,
                              void* d_out, int out_size, void* d_ws, size_t ws_size,
                              hipStream_t stream)
{
    const float* feats  = (const float*)d_in[0];
    const float* Wu     = (const float*)d_in[1];
    const float* Wv     = (const float*)d_in[2];
    const float* bv     = (const float*)d_in[3];
    const float* we     = (const float*)d_in[4];
    const int*   seg    = (const int*)d_in[5];
    const int*   counts = (const int*)d_in[6];
    const int N = in_sizes[0] / DD;
    const int B = in_sizes[6];

    char* w = (char*)d_ws;
    int*   offs = (int*)w;    w += ((size_t)B * sizeof(int) + 255) & ~(size_t)255;
    float* mean = (float*)w;  w += (size_t)B * DD * sizeof(float);
    float* amax = (float*)w;  w += (size_t)B * DD * sizeof(float);
    float* vtab = (float*)w;  w += (size_t)B * DD * sizeof(float);
    float* ee   = (float*)w;  w += (size_t)N * sizeof(float);

    k0_scan<<<1, 256, 0, stream>>>(counts, offs, B);
    k1_stats<<<B, 128, 0, stream>>>(feats, offs, counts, mean, amax);
    k2_vtab<<<(B + 15) / 16, 128, 0, stream>>>(mean, amax, Wv, bv, vtab, B);
    const int tiles = (N + 127) / 128;
    k3_gemm<<<tiles, 256, 128 * 132 * sizeof(float), stream>>>(feats, Wu, vtab, we, seg, ee, N);
    k4_pool<<<B, 128, 0, stream>>>(feats, ee, offs, counts, (float*)d_out);
}

// Round 2
// 368.435 us; speedup vs baseline: 2.0939x; 2.0939x over previous
//
#include <hip/hip_runtime.h>
#include <hip/hip_bf16.h>
#include <math.h>

#define DD 128

typedef __attribute__((ext_vector_type(8))) short bf16x8;
typedef __attribute__((ext_vector_type(4))) float f32x4;

static __device__ __forceinline__ short f2bf(float x) {
    union { float f; unsigned u; } v; v.f = x;
    unsigned r = v.u + 0x7FFFu + ((v.u >> 16) & 1u);   // RNE
    return (short)(r >> 16);
}

// ---------------- K0: exclusive prefix scan of counts -> offs ----------------
__global__ void k0_scan(const int* __restrict__ counts, int* __restrict__ offs, int B)
{
    __shared__ int part[256];
    int t = threadIdx.x;
    int chunk = (B + 255) >> 8;
    int s = 0;
    for (int i = 0; i < chunk; ++i) {
        int idx = t * chunk + i;
        if (idx < B) s += counts[idx];
    }
    part[t] = s;
    __syncthreads();
    for (int off = 1; off < 256; off <<= 1) {
        int val = (t >= off) ? part[t - off] : 0;
        __syncthreads();
        part[t] += val;
        __syncthreads();
    }
    int run = (t > 0) ? part[t - 1] : 0;
    for (int i = 0; i < chunk; ++i) {
        int idx = t * chunk + i;
        if (idx < B) { offs[idx] = run; run += counts[idx]; }
    }
}

// ---------------- K1: per-graph mean + absmax ----------------
__global__ __launch_bounds__(128)
void k1_stats(const float* __restrict__ feats, const int* __restrict__ offs,
              const int* __restrict__ counts, float* __restrict__ mean,
              float* __restrict__ amax)
{
    int g = blockIdx.x;
    int d = threadIdx.x;
    int s = offs[g], c = counts[g];
    const float* p = feats + (size_t)s * DD + d;
    float sum = 0.f, mx = 0.f;   // |v| >= 0 so 0-init == segment_max(|.|)
    for (int i = 0; i < c; ++i) {
        float v = p[(size_t)i * DD];
        sum += v;
        mx = fmaxf(mx, fabsf(v));
    }
    mean[(size_t)g * DD + d] = sum / (float)c;
    amax[(size_t)g * DD + d] = mx;
}

// ---------------- K2: v[g] = row(g) @ W_v + b_v ----------------
// row(g) = (g odd) ? amax[g/2] : mean[g/2]
__global__ __launch_bounds__(128)
void k2_vtab(const float* __restrict__ mean, const float* __restrict__ amax,
             const float* __restrict__ Wv, const float* __restrict__ bv,
             float* __restrict__ vtab, int B)
{
    __shared__ float rows[16][DD];
    int g0 = blockIdx.x * 16;
    int h = threadIdx.x;
    for (int i = 0; i < 16; ++i) {
        int g = g0 + i;
        float val = 0.f;
        if (g < B) {
            int gg = g >> 1;
            const float* src = (g & 1) ? &amax[(size_t)gg * DD] : &mean[(size_t)gg * DD];
            val = src[h];
        }
        rows[i][h] = val;
    }
    __syncthreads();
    float acc[16];
    float bvh = bv[h];
    #pragma unroll
    for (int i = 0; i < 16; ++i) acc[i] = bvh;
    for (int d = 0; d < DD; d += 2) {
        float w0 = Wv[(size_t)d * DD + h];
        float w1 = Wv[(size_t)(d + 1) * DD + h];
        #pragma unroll
        for (int i = 0; i < 16; ++i) {
            float2 r = *(const float2*)&rows[i][d];
            acc[i] = fmaf(r.x, w0, acc[i]);
            acc[i] = fmaf(r.y, w1, acc[i]);
        }
    }
    #pragma unroll
    for (int i = 0; i < 16; ++i) {
        int g = g0 + i;
        if (g < B) vtab[(size_t)g * DD + h] = acc[i];
    }
}

// ---------------- prep: WuT_bf16[h][k] = bf16(Wu[k][h]) ----------------
__global__ __launch_bounds__(256)
void k_prep(const float* __restrict__ Wu, short* __restrict__ wuT)
{
    int idx = blockIdx.x * 256 + threadIdx.x;      // 0 .. 16383
    int h = idx >> 7, k = idx & 127;
    wuT[(size_t)h * DD + k] = f2bf(Wu[(size_t)k * DD + h]);
}

// ---------------- K3: bf16 MFMA feats@Wu + sigmoid + dot(w_e) + exp -> ee ----------------
// 4 waves/block, 64 nodes/wave (4 ntiles of 16), full 128 H per wave.
// WuT staged in 32KB LDS with XOR swizzle byte ^= (row&7)<<4 (conflict-free ds_read_b128).
__global__ __launch_bounds__(256)
void k3_mfma(const float* __restrict__ feats, const short* __restrict__ wuT,
             const float* __restrict__ vtab, const float* __restrict__ we,
             const int* __restrict__ seg, float* __restrict__ ee, int N)
{
    __shared__ uint4 lds[2048];        // 32 KB swizzled WuT[h][k] bf16
    char* ldsb = (char*)lds;
    const int t = threadIdx.x;

    // stage WuT -> LDS (swizzled), 256 thr x 8 iters x 16B = 32KB
    #pragma unroll
    for (int it = 0; it < 8; ++it) {
        int c = it * 256 + t;                       // 16B-chunk id
        int row = c >> 4;                           // h
        int colb = (c & 15) * 16;                   // byte within row
        uint4 v = ((const uint4*)wuT)[c];
        *(uint4*)(ldsb + row * 256 + (colb ^ ((row & 7) << 4))) = v;
    }
    __syncthreads();

    const int lane = t & 63;
    const int w = t >> 6;
    const int l15 = lane & 15;
    const int kg = lane >> 4;                       // k-group 0..3
    const int wbase = blockIdx.x * 256 + w * 64;    // first node of this wave

    f32x4 acc[4][8];
    #pragma unroll
    for (int nt = 0; nt < 4; ++nt)
        #pragma unroll
        for (int ht = 0; ht < 8; ++ht)
            acc[nt][ht] = (f32x4){0.f, 0.f, 0.f, 0.f};

    #pragma unroll
    for (int ks = 0; ks < 4; ++ks) {
        // B fragments from swizzled LDS: WuT[h][ks*32+kg*8 .. +8]
        bf16x8 bf[8];
        #pragma unroll
        for (int ht = 0; ht < 8; ++ht) {
            int h = l15 + ht * 16;
            int kb = ks * 64 + kg * 16;             // byte offset of k-slice
            bf[ht] = *(const bf16x8*)(ldsb + h * 256 + (kb ^ ((h & 7) << 4)));
        }
        // A fragments straight from fp32 feats, packed to bf16 in regs
        bf16x8 fa[4];
        #pragma unroll
        for (int nt = 0; nt < 4; ++nt) {
            int row = wbase + nt * 16 + l15;
            row = (row < N) ? row : (N - 1);
            const float4* p = (const float4*)(feats + (size_t)row * DD + ks * 32 + kg * 8);
            float4 x0 = p[0], x1 = p[1];
            union { bf16x8 v; short s[8]; } u;
            u.s[0] = f2bf(x0.x); u.s[1] = f2bf(x0.y); u.s[2] = f2bf(x0.z); u.s[3] = f2bf(x0.w);
            u.s[4] = f2bf(x1.x); u.s[5] = f2bf(x1.y); u.s[6] = f2bf(x1.z); u.s[7] = f2bf(x1.w);
            fa[nt] = u.v;
        }
        #pragma unroll
        for (int nt = 0; nt < 4; ++nt)
            #pragma unroll
            for (int ht = 0; ht < 8; ++ht)
                acc[nt][ht] = __builtin_amdgcn_mfma_f32_16x16x32_bf16(fa[nt], bf[ht], acc[nt][ht], 0, 0, 0);
    }

    // epilogue: x = D + vtab[seg][h]; p = sum_h sigmoid(x)*we[h]; ee = exp(p)
    float wv[8];
    #pragma unroll
    for (int ht = 0; ht < 8; ++ht) wv[ht] = we[l15 + ht * 16];

    #pragma unroll
    for (int nt = 0; nt < 4; ++nt) {
        #pragma unroll
        for (int r = 0; r < 4; ++r) {
            int node = wbase + nt * 16 + kg * 4 + r;   // C layout: row=(lane>>4)*4+reg
            if (node < N) {
                int g = seg[node];
                const float* vg = vtab + (size_t)g * DD;
                float p = 0.f;
                #pragma unroll
                for (int ht = 0; ht < 8; ++ht) {
                    float x = acc[nt][ht][r] + vg[l15 + ht * 16];
                    float sg = 1.f / (1.f + __expf(-x));
                    p = fmaf(sg, wv[ht], p);
                }
                p += __shfl_xor(p, 1);
                p += __shfl_xor(p, 2);
                p += __shfl_xor(p, 4);
                p += __shfl_xor(p, 8);
                if (l15 == 0) ee[node] = (p != 0.f) ? __expf(p) : p;
            }
        }
    }
}

// ---------------- K4: attention-weighted pooling (fused denominator) ----------------
__global__ __launch_bounds__(128)
void k4_pool(const float* __restrict__ feats, const float* __restrict__ ee,
             const int* __restrict__ offs, const int* __restrict__ counts,
             float* __restrict__ out)
{
    int g = blockIdx.x;
    int d = threadIdx.x;
    int s = offs[g], c = counts[g];
    const float* p = feats + (size_t)s * DD + d;
    const float* w = ee + s;
    float acc = 0.f, den = 0.f;
    for (int i = 0; i < c; ++i) {
        float wi = w[i];
        den += wi;
        acc = fmaf(p[(size_t)i * DD], wi, acc);
    }
    out[(size_t)g * DD + d] = acc / den;
}

extern "C" void kernel_launch(void* const* d_in, const int* in_sizes, int n_in,
                              void* d_out, int out_size, void* d_ws, size_t ws_size,
                              hipStream_t stream)
{
    const float* feats  = (const float*)d_in[0];
    const float* Wu     = (const float*)d_in[1];
    const float* Wv     = (const float*)d_in[2];
    const float* bv     = (const float*)d_in[3];
    const float* we     = (const float*)d_in[4];
    const int*   seg    = (const int*)d_in[5];
    const int*   counts = (const int*)d_in[6];
    const int N = in_sizes[0] / DD;
    const int B = in_sizes[6];

    char* w = (char*)d_ws;
    int*   offs = (int*)w;    w += ((size_t)B * sizeof(int) + 255) & ~(size_t)255;
    float* mean = (float*)w;  w += (size_t)B * DD * sizeof(float);
    float* amax = (float*)w;  w += (size_t)B * DD * sizeof(float);
    float* vtab = (float*)w;  w += (size_t)B * DD * sizeof(float);
    float* ee   = (float*)w;  w += ((size_t)N * sizeof(float) + 255) & ~(size_t)255;
    short* wuT  = (short*)w;  w += (size_t)DD * DD * sizeof(short);

    k0_scan<<<1, 256, 0, stream>>>(counts, offs, B);
    k1_stats<<<B, 128, 0, stream>>>(feats, offs, counts, mean, amax);
    k2_vtab<<<(B + 15) / 16, 128, 0, stream>>>(mean, amax, Wv, bv, vtab, B);
    k_prep<<<64, 256, 0, stream>>>(Wu, wuT);

    const int nodes_per_block = 256;
    const int blocks = (N + nodes_per_block - 1) / nodes_per_block;
    k3_mfma<<<blocks, 256, 0, stream>>>(feats, wuT, vtab, we, seg, ee, N);

    k4_pool<<<B, 128, 0, stream>>>(feats, ee, offs, counts, (float*)d_out);
}

// Round 3
// 326.698 us; speedup vs baseline: 2.3615x; 1.1278x over previous
//
#include <hip/hip_runtime.h>
#include <hip/hip_bf16.h>
#include <math.h>

#define DD 128

typedef __attribute__((ext_vector_type(8))) short bf16x8;
typedef __attribute__((ext_vector_type(4))) float f32x4;

static __device__ __forceinline__ short f2bf(float x) {
    union { float f; unsigned u; } v; v.f = x;
    unsigned r = v.u + 0x7FFFu + ((v.u >> 16) & 1u);   // RNE
    return (short)(r >> 16);
}

// ---------------- K0: exclusive prefix scan of counts -> offs ----------------
__global__ void k0_scan(const int* __restrict__ counts, int* __restrict__ offs, int B)
{
    __shared__ int part[256];
    int t = threadIdx.x;
    int chunk = (B + 255) >> 8;
    int s = 0;
    for (int i = 0; i < chunk; ++i) {
        int idx = t * chunk + i;
        if (idx < B) s += counts[idx];
    }
    part[t] = s;
    __syncthreads();
    for (int off = 1; off < 256; off <<= 1) {
        int val = (t >= off) ? part[t - off] : 0;
        __syncthreads();
        part[t] += val;
        __syncthreads();
    }
    int run = (t > 0) ? part[t - 1] : 0;
    for (int i = 0; i < chunk; ++i) {
        int idx = t * chunk + i;
        if (idx < B) { offs[idx] = run; run += counts[idx]; }
    }
}

// ---------------- K1: per-graph mean + absmax (float2 lanes, 4-wave row stripe) ----------------
__global__ __launch_bounds__(256)
void k1_stats(const float* __restrict__ feats, const int* __restrict__ offs,
              const int* __restrict__ counts, float* __restrict__ mean,
              float* __restrict__ amax)
{
    int g = blockIdx.x;
    int s = offs[g], c = counts[g];
    int t = threadIdx.x, w = t >> 6, lane = t & 63;
    float sx = 0.f, sy = 0.f, mx = 0.f, my = 0.f;
    const float* base = feats + (size_t)s * DD + lane * 2;
    for (int i = w; i < c; i += 4) {
        float2 v = *(const float2*)(base + (size_t)i * DD);
        sx += v.x; sy += v.y;
        mx = fmaxf(mx, fabsf(v.x)); my = fmaxf(my, fabsf(v.y));
    }
    __shared__ float rs[4][DD];
    __shared__ float rm[4][DD];
    rs[w][lane * 2] = sx; rs[w][lane * 2 + 1] = sy;
    rm[w][lane * 2] = mx; rm[w][lane * 2 + 1] = my;
    __syncthreads();
    if (t < DD) {
        float ss = (rs[0][t] + rs[1][t]) + (rs[2][t] + rs[3][t]);
        float sm = fmaxf(fmaxf(rm[0][t], rm[1][t]), fmaxf(rm[2][t], rm[3][t]));
        mean[(size_t)g * DD + t] = ss / (float)c;
        amax[(size_t)g * DD + t] = sm;
    }
}

// ---------------- K2: vtab[g] = row(g) @ W_v + b_v ----------------
// row(g) = (g odd) ? amax[g/2] : mean[g/2]   (torch interleaved-table quirk)
__global__ __launch_bounds__(128)
void k2_vtab(const float* __restrict__ mean, const float* __restrict__ amax,
             const float* __restrict__ Wv, const float* __restrict__ bv,
             float* __restrict__ vtab, int B)
{
    __shared__ float rows[16][DD];
    int g0 = blockIdx.x * 16;
    int h = threadIdx.x;
    for (int i = 0; i < 16; ++i) {
        int g = g0 + i;
        float val = 0.f;
        if (g < B) {
            int gg = g >> 1;
            const float* src = (g & 1) ? &amax[(size_t)gg * DD] : &mean[(size_t)gg * DD];
            val = src[h];
        }
        rows[i][h] = val;
    }
    __syncthreads();
    float acc[16];
    float bvh = bv[h];
    #pragma unroll
    for (int i = 0; i < 16; ++i) acc[i] = bvh;
    for (int d = 0; d < DD; d += 2) {
        float w0 = Wv[(size_t)d * DD + h];
        float w1 = Wv[(size_t)(d + 1) * DD + h];
        #pragma unroll
        for (int i = 0; i < 16; ++i) {
            float2 r = *(const float2*)&rows[i][d];
            acc[i] = fmaf(r.x, w0, acc[i]);
            acc[i] = fmaf(r.y, w1, acc[i]);
        }
    }
    #pragma unroll
    for (int i = 0; i < 16; ++i) {
        int g = g0 + i;
        if (g < B) vtab[(size_t)g * DD + h] = acc[i];
    }
}

// ---------------- prep: WuT_bf16[h][k] = bf16(Wu[k][h]) ----------------
__global__ __launch_bounds__(256)
void k_prep(const float* __restrict__ Wu, short* __restrict__ wuT)
{
    int idx = blockIdx.x * 256 + threadIdx.x;
    int h = idx >> 7, k = idx & 127;
    wuT[(size_t)h * DD + k] = f2bf(Wu[(size_t)k * DD + h]);
}

// ---------------- KB: fused GEMM + sigmoid/w_e/exp + segment-normalize + pool ----------------
// One block per graph (c <= 126 nodes). feats staged fp32 in LDS with 32B-granule
// XOR swizzle (off ^= (row&7)<<5): A-frag reads and column-wise pooling both <=2-way.
__global__ __launch_bounds__(256)
void kb_fused(const float* __restrict__ feats, const short* __restrict__ wuT,
              const float* __restrict__ vtab, const float* __restrict__ we,
              const int* __restrict__ offs, const int* __restrict__ counts,
              float* __restrict__ out)
{
    __shared__ char fe[128 * 512];   // 64 KB swizzled fp32 feats tile
    __shared__ float eel[128];
    __shared__ float den_s;

    const int g = blockIdx.x;
    const int s = offs[g], c = counts[g];
    const int t = threadIdx.x;

    // stage graph's feats (contiguous slab) -> swizzled LDS
    const float4* src = (const float4*)(feats + (size_t)s * DD);
    for (int idx = t; idx < c * 32; idx += 256) {
        int row = idx >> 5, cq = idx & 31;
        float4 v = src[idx];
        *(float4*)(fe + row * 512 + ((cq * 16) ^ ((row & 7) << 5))) = v;
    }
    __syncthreads();

    const int w = t >> 6, lane = t & 63;
    const int l15 = lane & 15;
    const int kg = lane >> 4;

    f32x4 acc[2][8];
    #pragma unroll
    for (int nt = 0; nt < 2; ++nt)
        #pragma unroll
        for (int ht = 0; ht < 8; ++ht)
            acc[nt][ht] = (f32x4){0.f, 0.f, 0.f, 0.f};

    #pragma unroll
    for (int ks = 0; ks < 4; ++ks) {
        // B frags straight from L2-hot wuT[h][k]
        bf16x8 bf[8];
        #pragma unroll
        for (int ht = 0; ht < 8; ++ht)
            bf[ht] = *(const bf16x8*)(wuT + (size_t)(l15 + ht * 16) * DD + ks * 32 + kg * 8);
        // A frags from swizzled LDS, pack fp32->bf16
        bf16x8 fa[2];
        #pragma unroll
        for (int nt = 0; nt < 2; ++nt) {
            int row = w * 32 + nt * 16 + l15;
            int rr = (row < c) ? row : (c - 1);
            const char* pa = fe + rr * 512 + ((ks * 128 + kg * 32) ^ ((rr & 7) << 5));
            float4 x0 = *(const float4*)pa;
            float4 x1 = *(const float4*)(pa + 16);
            union { bf16x8 v; short sh[8]; } u;
            u.sh[0] = f2bf(x0.x); u.sh[1] = f2bf(x0.y); u.sh[2] = f2bf(x0.z); u.sh[3] = f2bf(x0.w);
            u.sh[4] = f2bf(x1.x); u.sh[5] = f2bf(x1.y); u.sh[6] = f2bf(x1.z); u.sh[7] = f2bf(x1.w);
            fa[nt] = u.v;
        }
        #pragma unroll
        for (int nt = 0; nt < 2; ++nt)
            #pragma unroll
            for (int ht = 0; ht < 8; ++ht)
                acc[nt][ht] = __builtin_amdgcn_mfma_f32_16x16x32_bf16(fa[nt], bf[ht], acc[nt][ht], 0, 0, 0);
    }

    // epilogue: logit -> ee (LDS)
    {
        float wv[8];
        #pragma unroll
        for (int ht = 0; ht < 8; ++ht) wv[ht] = we[l15 + ht * 16];
        const float* vg = vtab + (size_t)g * DD;
        #pragma unroll
        for (int nt = 0; nt < 2; ++nt) {
            #pragma unroll
            for (int r = 0; r < 4; ++r) {
                int node = w * 32 + nt * 16 + kg * 4 + r;   // C layout: row=(lane>>4)*4+reg
                float p = 0.f;
                #pragma unroll
                for (int ht = 0; ht < 8; ++ht) {
                    float x = acc[nt][ht][r] + vg[l15 + ht * 16];
                    float sg = 1.f / (1.f + __expf(-x));
                    p = fmaf(sg, wv[ht], p);
                }
                p += __shfl_xor(p, 1);
                p += __shfl_xor(p, 2);
                p += __shfl_xor(p, 4);
                p += __shfl_xor(p, 8);
                if (l15 == 0 && node < c)
                    eel[node] = (p != 0.f) ? __expf(p) : p;
            }
        }
    }
    __syncthreads();

    // denominator
    if (t < 64) {
        float v = ((t < c) ? eel[t] : 0.f) + ((t + 64 < c) ? eel[t + 64] : 0.f);
        v += __shfl_xor(v, 1);
        v += __shfl_xor(v, 2);
        v += __shfl_xor(v, 4);
        v += __shfl_xor(v, 8);
        v += __shfl_xor(v, 16);
        v += __shfl_xor(v, 32);
        if (t == 0) den_s = v;
    }
    __syncthreads();

    // pooling: out[g][d] = sum_i feats[i][d]*ee[i] / den
    if (t < DD) {
        float inv_den = 1.f / den_s;
        float acc2 = 0.f;
        #pragma unroll 4
        for (int i = 0; i < c; ++i) {
            float fv = *(const float*)(fe + i * 512 + ((t * 4) ^ ((i & 7) << 5)));
            acc2 = fmaf(fv, eel[i], acc2);
        }
        out[(size_t)g * DD + t] = acc2 * inv_den;
    }
}

extern "C" void kernel_launch(void* const* d_in, const int* in_sizes, int n_in,
                              void* d_out, int out_size, void* d_ws, size_t ws_size,
                              hipStream_t stream)
{
    const float* feats  = (const float*)d_in[0];
    const float* Wu     = (const float*)d_in[1];
    const float* Wv     = (const float*)d_in[2];
    const float* bv     = (const float*)d_in[3];
    const float* we     = (const float*)d_in[4];
    const int*   counts = (const int*)d_in[6];
    const int B = in_sizes[6];

    char* w = (char*)d_ws;
    int*   offs = (int*)w;    w += ((size_t)B * sizeof(int) + 255) & ~(size_t)255;
    float* mean = (float*)w;  w += (size_t)B * DD * sizeof(float);
    float* amax = (float*)w;  w += (size_t)B * DD * sizeof(float);
    float* vtab = (float*)w;  w += (size_t)B * DD * sizeof(float);
    short* wuT  = (short*)w;  w += (size_t)DD * DD * sizeof(short);

    k0_scan<<<1, 256, 0, stream>>>(counts, offs, B);
    k1_stats<<<B, 256, 0, stream>>>(feats, offs, counts, mean, amax);
    k2_vtab<<<(B + 15) / 16, 128, 0, stream>>>(mean, amax, Wv, bv, vtab, B);
    k_prep<<<64, 256, 0, stream>>>(Wu, wuT);
    kb_fused<<<B, 256, 0, stream>>>(feats, wuT, vtab, we, offs, counts, (float*)d_out);
}

// Round 4
// 281.849 us; speedup vs baseline: 2.7372x; 1.1591x over previous
//
#include <hip/hip_runtime.h>
#include <hip/hip_bf16.h>
#include <math.h>

#define DD 128

typedef __attribute__((ext_vector_type(8))) short bf16x8;
typedef __attribute__((ext_vector_type(4))) float f32x4;

static __device__ __forceinline__ short f2bf(float x) {
    union { float f; unsigned u; } v; v.f = x;
    unsigned r = v.u + 0x7FFFu + ((v.u >> 16) & 1u);   // RNE
    return (short)(r >> 16);
}

// ---------------- K0: block 0 = prefix scan; blocks 1..64 = WuT bf16 prep ----------------
__global__ void k0_combined(const int* __restrict__ counts, int* __restrict__ offs, int B,
                            const float* __restrict__ Wu, short* __restrict__ wuT)
{
    if (blockIdx.x == 0) {
        __shared__ int part[256];
        int t = threadIdx.x;
        int chunk = (B + 255) >> 8;
        int s = 0;
        for (int i = 0; i < chunk; ++i) {
            int idx = t * chunk + i;
            if (idx < B) s += counts[idx];
        }
        part[t] = s;
        __syncthreads();
        for (int off = 1; off < 256; off <<= 1) {
            int val = (t >= off) ? part[t - off] : 0;
            __syncthreads();
            part[t] += val;
            __syncthreads();
        }
        int run = (t > 0) ? part[t - 1] : 0;
        for (int i = 0; i < chunk; ++i) {
            int idx = t * chunk + i;
            if (idx < B) { offs[idx] = run; run += counts[idx]; }
        }
    } else {
        int idx = (blockIdx.x - 1) * 256 + threadIdx.x;   // 0..16383
        int h = idx >> 7, k = idx & 127;
        wuT[(size_t)h * DD + k] = f2bf(Wu[(size_t)k * DD + h]);
    }
}

// ---------------- K1: per-graph mean + absmax (float4 lanes, 8-row stripe) ----------------
__global__ __launch_bounds__(256)
void k1_stats(const float* __restrict__ feats, const int* __restrict__ offs,
              const int* __restrict__ counts, float* __restrict__ mean,
              float* __restrict__ amax)
{
    int g = blockIdx.x;
    int s = offs[g], c = counts[g];
    int t = threadIdx.x;
    int col = (t & 31) * 4;          // float4 column
    int r0 = t >> 5;                 // 0..7
    float4 sm = {0.f, 0.f, 0.f, 0.f};
    float4 mx = {0.f, 0.f, 0.f, 0.f};
    const float* base = feats + (size_t)s * DD + col;
    #pragma unroll 4
    for (int i = r0; i < c; i += 8) {
        float4 v = *(const float4*)(base + (size_t)i * DD);
        sm.x += v.x; sm.y += v.y; sm.z += v.z; sm.w += v.w;
        mx.x = fmaxf(mx.x, fabsf(v.x)); mx.y = fmaxf(mx.y, fabsf(v.y));
        mx.z = fmaxf(mx.z, fabsf(v.z)); mx.w = fmaxf(mx.w, fabsf(v.w));
    }
    __shared__ float ls[8][DD];
    __shared__ float lm[8][DD];
    *(float4*)&ls[r0][col] = sm;
    *(float4*)&lm[r0][col] = mx;
    __syncthreads();
    if (t < DD) {
        float ss = 0.f, mm = 0.f;
        #pragma unroll
        for (int r = 0; r < 8; ++r) {
            ss += ls[r][t];
            mm = fmaxf(mm, lm[r][t]);
        }
        mean[(size_t)g * DD + t] = ss / (float)c;
        amax[(size_t)g * DD + t] = mm;
    }
}

// ---------------- K2: vtab[g] = row(g) @ W_v + b_v ----------------
// row(g) = (g odd) ? amax[g/2] : mean[g/2]   (torch interleaved-table quirk)
__global__ __launch_bounds__(128)
void k2_vtab(const float* __restrict__ mean, const float* __restrict__ amax,
             const float* __restrict__ Wv, const float* __restrict__ bv,
             float* __restrict__ vtab, int B)
{
    __shared__ float rows[16][DD];
    int g0 = blockIdx.x * 16;
    int h = threadIdx.x;
    for (int i = 0; i < 16; ++i) {
        int g = g0 + i;
        float val = 0.f;
        if (g < B) {
            int gg = g >> 1;
            const float* src = (g & 1) ? &amax[(size_t)gg * DD] : &mean[(size_t)gg * DD];
            val = src[h];
        }
        rows[i][h] = val;
    }
    __syncthreads();
    float acc[16];
    float bvh = bv[h];
    #pragma unroll
    for (int i = 0; i < 16; ++i) acc[i] = bvh;
    for (int d = 0; d < DD; d += 2) {
        float w0 = Wv[(size_t)d * DD + h];
        float w1 = Wv[(size_t)(d + 1) * DD + h];
        #pragma unroll
        for (int i = 0; i < 16; ++i) {
            float2 r = *(const float2*)&rows[i][d];
            acc[i] = fmaf(r.x, w0, acc[i]);
            acc[i] = fmaf(r.y, w1, acc[i]);
        }
    }
    #pragma unroll
    for (int i = 0; i < 16; ++i) {
        int g = g0 + i;
        if (g < B) vtab[(size_t)g * DD + h] = acc[i];
    }
}

// ---------------- KB: fused GEMM + sigmoid/w_e/exp + segment-normalize + pool ----------------
// One block (256 thr) per graph, c <= 126. No feats staging: A-fragments and the
// pooling pass both read global (L1/L2-hot slab). Wave w owns node tiles {w, w+4}.
__global__ __launch_bounds__(256)
void kb_fused(const float* __restrict__ feats, const short* __restrict__ wuT,
              const float* __restrict__ vtab, const float* __restrict__ we,
              const int* __restrict__ offs, const int* __restrict__ counts,
              float* __restrict__ out)
{
    __shared__ float eel[128];
    __shared__ float pool[4][DD];
    __shared__ float dparts[4];

    const int g = blockIdx.x;
    const int s = offs[g], c = counts[g];
    const int t = threadIdx.x;
    const int w = t >> 6, lane = t & 63;
    const int l15 = lane & 15, kg = lane >> 4;

    const int tb0 = w * 16;
    const int tb1 = (w + 4) * 16;
    const int nact = (tb1 < c) ? 2 : ((tb0 < c) ? 1 : 0);

    f32x4 acc[2][8];
    #pragma unroll
    for (int nt = 0; nt < 2; ++nt)
        #pragma unroll
        for (int ht = 0; ht < 8; ++ht)
            acc[nt][ht] = (f32x4){0.f, 0.f, 0.f, 0.f};

    if (nact > 0) {
        // clamped global rows for the two tiles
        int r0 = tb0 + l15; r0 = (r0 < c) ? r0 : (c - 1);
        int r1 = tb1 + l15; r1 = (r1 < c) ? r1 : (c - 1);
        const float* a0p = feats + (size_t)(s + r0) * DD;
        const float* a1p = feats + (size_t)(s + r1) * DD;
        const short* bp = wuT + (size_t)l15 * DD + kg * 8;

        #pragma unroll
        for (int ks = 0; ks < 4; ++ks) {
            const int ko = ks * 32 + kg * 8;
            // A fragments (fp32 global -> bf16 regs)
            bf16x8 fa[2];
            {
                float4 x0 = *(const float4*)(a0p + ko);
                float4 x1 = *(const float4*)(a0p + ko + 4);
                union { bf16x8 v; short sh[8]; } u;
                u.sh[0] = f2bf(x0.x); u.sh[1] = f2bf(x0.y); u.sh[2] = f2bf(x0.z); u.sh[3] = f2bf(x0.w);
                u.sh[4] = f2bf(x1.x); u.sh[5] = f2bf(x1.y); u.sh[6] = f2bf(x1.z); u.sh[7] = f2bf(x1.w);
                fa[0] = u.v;
            }
            if (nact > 1) {
                float4 x0 = *(const float4*)(a1p + ko);
                float4 x1 = *(const float4*)(a1p + ko + 4);
                union { bf16x8 v; short sh[8]; } u;
                u.sh[0] = f2bf(x0.x); u.sh[1] = f2bf(x0.y); u.sh[2] = f2bf(x0.z); u.sh[3] = f2bf(x0.w);
                u.sh[4] = f2bf(x1.x); u.sh[5] = f2bf(x1.y); u.sh[6] = f2bf(x1.z); u.sh[7] = f2bf(x1.w);
                fa[1] = u.v;
            }
            // B fragments from L1-hot wuT
            bf16x8 bf[8];
            #pragma unroll
            for (int ht = 0; ht < 8; ++ht)
                bf[ht] = *(const bf16x8*)(bp + (size_t)(ht * 16) * DD + ks * 32);
            #pragma unroll
            for (int ht = 0; ht < 8; ++ht) {
                acc[0][ht] = __builtin_amdgcn_mfma_f32_16x16x32_bf16(fa[0], bf[ht], acc[0][ht], 0, 0, 0);
                if (nact > 1)
                    acc[1][ht] = __builtin_amdgcn_mfma_f32_16x16x32_bf16(fa[1], bf[ht], acc[1][ht], 0, 0, 0);
            }
        }

        // epilogue: logit -> ee (LDS)
        float wv[8], vgv[8];
        #pragma unroll
        for (int ht = 0; ht < 8; ++ht) {
            wv[ht]  = we[l15 + ht * 16];
            vgv[ht] = vtab[(size_t)g * DD + l15 + ht * 16];
        }
        #pragma unroll
        for (int nt = 0; nt < 2; ++nt) {
            if (nt < nact) {
                const int tb = (nt == 0) ? tb0 : tb1;
                #pragma unroll
                for (int r = 0; r < 4; ++r) {
                    int node = tb + kg * 4 + r;    // C layout: row=(lane>>4)*4+reg
                    float p = 0.f;
                    #pragma unroll
                    for (int ht = 0; ht < 8; ++ht) {
                        float x = acc[nt][ht][r] + vgv[ht];
                        float sg = 1.f / (1.f + __expf(-x));
                        p = fmaf(sg, wv[ht], p);
                    }
                    p += __shfl_xor(p, 1);
                    p += __shfl_xor(p, 2);
                    p += __shfl_xor(p, 4);
                    p += __shfl_xor(p, 8);
                    if (l15 == 0 && node < c)
                        eel[node] = (p != 0.f) ? __expf(p) : p;
                }
            }
        }
    }
    __syncthreads();

    // pooling + fused denominator: wave w handles rows i = w, w+4, ...
    {
        float2 pl = {0.f, 0.f};
        float dw = 0.f;
        const float* base = feats + (size_t)s * DD + lane * 2;
        #pragma unroll 4
        for (int i = w; i < c; i += 4) {
            float wi = eel[i];
            float2 v = *(const float2*)(base + (size_t)i * DD);
            dw += wi;
            pl.x = fmaf(v.x, wi, pl.x);
            pl.y = fmaf(v.y, wi, pl.y);
        }
        pool[w][lane * 2]     = pl.x;
        pool[w][lane * 2 + 1] = pl.y;
        if (lane == 0) dparts[w] = dw;
    }
    __syncthreads();

    if (t < DD) {
        float den = (dparts[0] + dparts[1]) + (dparts[2] + dparts[3]);
        float acc2 = ((pool[0][t] + pool[1][t]) + (pool[2][t] + pool[3][t]));
        out[(size_t)g * DD + t] = acc2 / den;
    }
}

extern "C" void kernel_launch(void* const* d_in, const int* in_sizes, int n_in,
                              void* d_out, int out_size, void* d_ws, size_t ws_size,
                              hipStream_t stream)
{
    const float* feats  = (const float*)d_in[0];
    const float* Wu     = (const float*)d_in[1];
    const float* Wv     = (const float*)d_in[2];
    const float* bv     = (const float*)d_in[3];
    const float* we     = (const float*)d_in[4];
    const int*   counts = (const int*)d_in[6];
    const int B = in_sizes[6];

    char* w = (char*)d_ws;
    int*   offs = (int*)w;    w += ((size_t)B * sizeof(int) + 255) & ~(size_t)255;
    float* mean = (float*)w;  w += (size_t)B * DD * sizeof(float);
    float* amax = (float*)w;  w += (size_t)B * DD * sizeof(float);
    float* vtab = (float*)w;  w += (size_t)B * DD * sizeof(float);
    short* wuT  = (short*)w;  w += (size_t)DD * DD * sizeof(short);

    k0_combined<<<65, 256, 0, stream>>>(counts, offs, B, Wu, wuT);
    k1_stats<<<B, 256, 0, stream>>>(feats, offs, counts, mean, amax);
    k2_vtab<<<(B + 15) / 16, 128, 0, stream>>>(mean, amax, Wv, bv, vtab, B);
    kb_fused<<<B, 256, 0, stream>>>(feats, wuT, vtab, we, offs, counts, (float*)d_out);
}

// Round 5
// 250.277 us; speedup vs baseline: 3.0825x; 1.1261x over previous
//
#include <hip/hip_runtime.h>
#include <hip/hip_bf16.h>
#include <math.h>

#define DD 128

typedef __attribute__((ext_vector_type(8))) short bf16x8;
typedef __attribute__((ext_vector_type(4))) float f32x4;

static __device__ __forceinline__ short f2bf(float x) {
    union { float f; unsigned u; } v; v.f = x;
    unsigned r = v.u + 0x7FFFu + ((v.u >> 16) & 1u);   // RNE
    return (short)(r >> 16);
}
static __device__ __forceinline__ float bf2f(unsigned short h) {
    union { unsigned u; float f; } v; v.u = ((unsigned)h) << 16;
    return v.f;
}

// ---------------- K0: block 0 = prefix scan; blocks 1..64 = WuT bf16 prep ----------------
__global__ void k0_combined(const int* __restrict__ counts, int* __restrict__ offs, int B,
                            const float* __restrict__ Wu, short* __restrict__ wuT)
{
    if (blockIdx.x == 0) {
        __shared__ int part[256];
        int t = threadIdx.x;
        int chunk = (B + 255) >> 8;
        int s = 0;
        for (int i = 0; i < chunk; ++i) {
            int idx = t * chunk + i;
            if (idx < B) s += counts[idx];
        }
        part[t] = s;
        __syncthreads();
        for (int off = 1; off < 256; off <<= 1) {
            int val = (t >= off) ? part[t - off] : 0;
            __syncthreads();
            part[t] += val;
            __syncthreads();
        }
        int run = (t > 0) ? part[t - 1] : 0;
        for (int i = 0; i < chunk; ++i) {
            int idx = t * chunk + i;
            if (idx < B) { offs[idx] = run; run += counts[idx]; }
        }
    } else {
        int idx = (blockIdx.x - 1) * 256 + threadIdx.x;   // 0..16383
        int h = idx >> 7, k = idx & 127;
        wuT[(size_t)h * DD + k] = f2bf(Wu[(size_t)k * DD + h]);
    }
}

// ---------------- K1: per-graph mean + absmax (float4 lanes, 8-row stripe) ----------------
__global__ __launch_bounds__(256)
void k1_stats(const float* __restrict__ feats, const int* __restrict__ offs,
              const int* __restrict__ counts, float* __restrict__ mean,
              float* __restrict__ amax)
{
    int g = blockIdx.x;
    int s = offs[g], c = counts[g];
    int t = threadIdx.x;
    int col = (t & 31) * 4;          // float4 column
    int r0 = t >> 5;                 // 0..7
    float4 sm = {0.f, 0.f, 0.f, 0.f};
    float4 mx = {0.f, 0.f, 0.f, 0.f};
    const float* base = feats + (size_t)s * DD + col;
    #pragma unroll 4
    for (int i = r0; i < c; i += 8) {
        float4 v = *(const float4*)(base + (size_t)i * DD);
        sm.x += v.x; sm.y += v.y; sm.z += v.z; sm.w += v.w;
        mx.x = fmaxf(mx.x, fabsf(v.x)); mx.y = fmaxf(mx.y, fabsf(v.y));
        mx.z = fmaxf(mx.z, fabsf(v.z)); mx.w = fmaxf(mx.w, fabsf(v.w));
    }
    __shared__ float ls[8][DD];
    __shared__ float lm[8][DD];
    *(float4*)&ls[r0][col] = sm;
    *(float4*)&lm[r0][col] = mx;
    __syncthreads();
    if (t < DD) {
        float ss = 0.f, mm = 0.f;
        #pragma unroll
        for (int r = 0; r < 8; ++r) {
            ss += ls[r][t];
            mm = fmaxf(mm, lm[r][t]);
        }
        mean[(size_t)g * DD + t] = ss / (float)c;
        amax[(size_t)g * DD + t] = mm;
    }
}

// ---------------- K2: vtab[g] = row(g) @ W_v + b_v ----------------
// row(g) = (g odd) ? amax[g/2] : mean[g/2]   (torch interleaved-table quirk)
__global__ __launch_bounds__(128)
void k2_vtab(const float* __restrict__ mean, const float* __restrict__ amax,
             const float* __restrict__ Wv, const float* __restrict__ bv,
             float* __restrict__ vtab, int B)
{
    __shared__ float rows[16][DD];
    int g0 = blockIdx.x * 16;
    int h = threadIdx.x;
    for (int i = 0; i < 16; ++i) {
        int g = g0 + i;
        float val = 0.f;
        if (g < B) {
            int gg = g >> 1;
            const float* src = (g & 1) ? &amax[(size_t)gg * DD] : &mean[(size_t)gg * DD];
            val = src[h];
        }
        rows[i][h] = val;
    }
    __syncthreads();
    float acc[16];
    float bvh = bv[h];
    #pragma unroll
    for (int i = 0; i < 16; ++i) acc[i] = bvh;
    for (int d = 0; d < DD; d += 2) {
        float w0 = Wv[(size_t)d * DD + h];
        float w1 = Wv[(size_t)(d + 1) * DD + h];
        #pragma unroll
        for (int i = 0; i < 16; ++i) {
            float2 r = *(const float2*)&rows[i][d];
            acc[i] = fmaf(r.x, w0, acc[i]);
            acc[i] = fmaf(r.y, w1, acc[i]);
        }
    }
    #pragma unroll
    for (int i = 0; i < 16; ++i) {
        int g = g0 + i;
        if (g < B) vtab[(size_t)g * DD + h] = acc[i];
    }
}

// ---------------- KB: fused GEMM + sigmoid/w_e/exp + segment-normalize + pool ----------------
// One block per graph. feats staged ONCE as bf16 in LDS (dense coalesced stream),
// GEMM A-frags and pooling both read LDS. One 16-node tile per wave per pass
// (32 AGPR acc) + launch_bounds(256,4) -> 4 waves/SIMD, ~4 blocks/CU.
__global__ __launch_bounds__(256, 4)
void kb_fused(const float* __restrict__ feats, const short* __restrict__ wuT,
              const float* __restrict__ vtab, const float* __restrict__ we,
              const int* __restrict__ offs, const int* __restrict__ counts,
              float* __restrict__ out)
{
    __shared__ short fe[128 * 128];   // 32 KB bf16, swizzled [row][128]
    __shared__ float eel[128];
    __shared__ float red[4][DD];
    __shared__ float dparts[4];

    const int g = blockIdx.x;
    const int s = offs[g], c = counts[g];
    const int t = threadIdx.x;
    const int w = t >> 6, lane = t & 63;
    const int l15 = lane & 15, kg = lane >> 4;
    char* feb = (char*)fe;

    // ---- stage: feats slab -> bf16 LDS (16B chunks, XOR swizzle ^(row&7)<<4) ----
    const int cpad = (c + 15) & ~15;
    const int nch = cpad * 16;                    // 16B-bf16 chunks
    #pragma unroll 2
    for (int ch = t; ch < nch; ch += 256) {
        int row = ch >> 4, sub = ch & 15;
        union { bf16x8 v; short sh[8]; } u;
        if (row < c) {
            const float4* gp = (const float4*)(feats + (size_t)(s + row) * DD + sub * 8);
            float4 a = gp[0], b = gp[1];
            u.sh[0] = f2bf(a.x); u.sh[1] = f2bf(a.y); u.sh[2] = f2bf(a.z); u.sh[3] = f2bf(a.w);
            u.sh[4] = f2bf(b.x); u.sh[5] = f2bf(b.y); u.sh[6] = f2bf(b.z); u.sh[7] = f2bf(b.w);
        } else {
            u.v = (bf16x8){0, 0, 0, 0, 0, 0, 0, 0};
        }
        *(bf16x8*)(feb + row * 256 + ((sub * 16) ^ ((row & 7) << 4))) = u.v;
    }
    __syncthreads();

    // epilogue constants
    float wv[8], vgv[8];
    #pragma unroll
    for (int ht = 0; ht < 8; ++ht) {
        wv[ht]  = we[l15 + ht * 16];
        vgv[ht] = vtab[(size_t)g * DD + l15 + ht * 16];
    }

    // ---- GEMM + logit epilogue, one 16-node tile per wave per pass ----
    #pragma unroll
    for (int p = 0; p < 2; ++p) {
        const int tb = (w + p * 4) * 16;
        if (tb < c) {
            bf16x8 af[4];
            #pragma unroll
            for (int ks = 0; ks < 4; ++ks)
                af[ks] = *(const bf16x8*)(feb + (tb + l15) * 256 +
                                          ((ks * 64 + kg * 16) ^ ((l15 & 7) << 4)));
            f32x4 acc[8];
            #pragma unroll
            for (int ht = 0; ht < 8; ++ht) acc[ht] = (f32x4){0.f, 0.f, 0.f, 0.f};
            #pragma unroll
            for (int ks = 0; ks < 4; ++ks) {
                #pragma unroll
                for (int ht = 0; ht < 8; ++ht) {
                    bf16x8 bfr = *(const bf16x8*)(wuT + (size_t)(l15 + ht * 16) * DD + ks * 32 + kg * 8);
                    acc[ht] = __builtin_amdgcn_mfma_f32_16x16x32_bf16(af[ks], bfr, acc[ht], 0, 0, 0);
                }
            }
            #pragma unroll
            for (int r = 0; r < 4; ++r) {
                int node = tb + kg * 4 + r;          // C layout: row=(lane>>4)*4+reg
                float pp = 0.f;
                #pragma unroll
                for (int ht = 0; ht < 8; ++ht) {
                    float x = acc[ht][r] + vgv[ht];
                    float sg = 1.f / (1.f + __expf(-x));
                    pp = fmaf(sg, wv[ht], pp);
                }
                pp += __shfl_xor(pp, 1);
                pp += __shfl_xor(pp, 2);
                pp += __shfl_xor(pp, 4);
                pp += __shfl_xor(pp, 8);
                if (l15 == 0 && node < c)
                    eel[node] = (pp != 0.f) ? __expf(pp) : pp;
            }
        }
    }
    __syncthreads();

    // ---- pooling + denominator from LDS (bf16 feats, fp32 accum) ----
    {
        float px = 0.f, py = 0.f, dw = 0.f;
        #pragma unroll 4
        for (int i = w; i < c; i += 4) {
            unsigned pv = *(const unsigned*)(feb + i * 256 + ((lane * 4) ^ ((i & 7) << 4)));
            float wi = eel[i];
            dw += wi;
            px = fmaf(bf2f((unsigned short)(pv & 0xffffu)), wi, px);
            py = fmaf(bf2f((unsigned short)(pv >> 16)), wi, py);
        }
        red[w][lane * 2]     = px;
        red[w][lane * 2 + 1] = py;
        if (lane == 0) dparts[w] = dw;
    }
    __syncthreads();

    if (t < DD) {
        float den = (dparts[0] + dparts[1]) + (dparts[2] + dparts[3]);
        float a2 = (red[0][t] + red[1][t]) + (red[2][t] + red[3][t]);
        out[(size_t)g * DD + t] = a2 / den;
    }
}

extern "C" void kernel_launch(void* const* d_in, const int* in_sizes, int n_in,
                              void* d_out, int out_size, void* d_ws, size_t ws_size,
                              hipStream_t stream)
{
    const float* feats  = (const float*)d_in[0];
    const float* Wu     = (const float*)d_in[1];
    const float* Wv     = (const float*)d_in[2];
    const float* bv     = (const float*)d_in[3];
    const float* we     = (const float*)d_in[4];
    const int*   counts = (const int*)d_in[6];
    const int B = in_sizes[6];

    char* w = (char*)d_ws;
    int*   offs = (int*)w;    w += ((size_t)B * sizeof(int) + 255) & ~(size_t)255;
    float* mean = (float*)w;  w += (size_t)B * DD * sizeof(float);
    float* amax = (float*)w;  w += (size_t)B * DD * sizeof(float);
    float* vtab = (float*)w;  w += (size_t)B * DD * sizeof(float);
    short* wuT  = (short*)w;  w += (size_t)DD * DD * sizeof(short);

    k0_combined<<<65, 256, 0, stream>>>(counts, offs, B, Wu, wuT);
    k1_stats<<<B, 256, 0, stream>>>(feats, offs, counts, mean, amax);
    k2_vtab<<<(B + 15) / 16, 128, 0, stream>>>(mean, amax, Wv, bv, vtab, B);
    kb_fused<<<B, 256, 0, stream>>>(feats, wuT, vtab, we, offs, counts, (float*)d_out);
}